// Round 3
// baseline (106.504 us; speedup 1.0000x reference)
//
#include <hip/hip_runtime.h>
#include <math.h>

#define NB 32
#define CC 64
#define LL 1024
#define EPS 1e-6f

typedef __attribute__((ext_vector_type(8))) __bf16 bf16x8;
typedef __attribute__((ext_vector_type(4))) float f32x4;

// ws byte layout:
//   At      @ 0         (4 MB)   bf16 [32][1024][64]  normalized rgb, [l][c]
//   Bt      @ 4194304   (4 MB)   bf16 [32][1024][64]  normalized ir,  [l][c]
//   row_sum @ 8388608   (128 KB) f32[32768]
//   col_sum @ 8519680   (128 KB) f32[32768]
//   row_pk  @ 8650752   (128 KB) u32[32768]  (expbits&~1023)|(1023-j)
//   col_pk  @ 8781824   (128 KB) u32[32768]  (expbits&~1023)|(1023-i)
//   loss    @ 8912896   (4 B)
// Stats region (row_sum..loss) = 131073 dwords, zeroed inside transpose_norm.

// Grid 1024 = input(2) x batch(32) x lchunk(16). Per-pixel inverse channel
// norms, scale, bf16 convert, write transposed [l][c] (128 B rows = exactly
// MFMA A/B-fragment order). Also zeroes the stats region (ws is 0xAA-poisoned
// before every launch; this kernel always runs first).
__global__ __launch_bounds__(256) void transpose_norm_kernel(
        const float* __restrict__ rgb, const float* __restrict__ ir,
        __bf16* __restrict__ At, __bf16* __restrict__ Bt,
        float* __restrict__ stats_base) {
    __shared__ float tile[64][65];
    __shared__ float red[4][64];
    __shared__ float rn[64];

    const int t   = threadIdx.x;
    const int blk = blockIdx.x;

    // fold the stats-zeroing memset into this kernel (saves a dispatch)
    int zid = blk * 256 + t;
    if (zid <= 131072) stats_base[zid] = 0.f;

    const int in  = blk >> 9;
    const int b   = (blk >> 4) & 31;
    const int l0  = (blk & 15) << 6;
    const float* src = in ? ir : rgb;
    __bf16*      dst = in ? Bt : At;

    const int ll = t & 63, cg = t >> 6;
    const float* sp = src + ((size_t)b << 16) + l0 + ll;
#pragma unroll
    for (int u = 0; u < 16; ++u) {
        int c = cg * 16 + u;
        tile[c][ll] = sp[(size_t)c << 10];      // coalesced 256B per 64-lane run
    }
    __syncthreads();

    float ssq = 0.f;
#pragma unroll
    for (int u = 0; u < 16; ++u) {
        float v = tile[cg * 16 + u][ll];
        ssq = fmaf(v, v, ssq);
    }
    red[cg][ll] = ssq;
    __syncthreads();
    if (t < 64) {
        float s = red[0][t] + red[1][t] + red[2][t] + red[3][t];
        rn[t] = 1.0f / fmaxf(sqrtf(s), 1e-12f);
    }
    __syncthreads();

    const int lw  = t >> 2;
    const int cg2 = t & 3;
    const float r = rn[lw];
    bf16x8 v0, v1;
#pragma unroll
    for (int u = 0; u < 8; ++u)
        v0[u] = (__bf16)(tile[cg2 * 16 + u][lw] * r);
#pragma unroll
    for (int u = 0; u < 8; ++u)
        v1[u] = (__bf16)(tile[cg2 * 16 + 8 + u][lw] * r);
    size_t base = ((((size_t)b << 10) + l0 + lw) << 6) + cg2 * 16;
    *(bf16x8*)(dst + base)     = v0;
    *(bf16x8*)(dst + base + 8) = v1;
}

// Grid 2048 = batch(32) x itile(8) x jtile(8); 128x128 tile per block, 4 waves.
// NO LDS staging: At/Bt rows are already exact MFMA fragment layout; fragment
// reads are coalesced global_load_dwordx4, B-frags L1-hit across the 4 waves
// (fragment reuse within a block is 1, so LDS round-trip buys nothing and its
// barriers cost ~20% — round-2 lesson). Only 1 KB LDS for col-stat combine.
// Stats use packed u32 (expbits&~1023)|(1023-idx): one v_max_u32 gives
// max+first-index-argmax simultaneously.
__global__ __launch_bounds__(256) void gemm_stats_kernel(
        const __bf16* __restrict__ At, const __bf16* __restrict__ Bt,
        float* __restrict__ row_sum, unsigned* __restrict__ row_pk,
        float* __restrict__ col_sum, unsigned* __restrict__ col_pk) {
    __shared__ float    colsum_s[128];
    __shared__ unsigned colpk_s[128];

    const int t   = threadIdx.x;
    const int blk = blockIdx.x;
    const int bb  = blk >> 6;
    const int i0  = ((blk >> 3) & 7) << 7;
    const int j0  = (blk & 7) << 7;
    const int w = t >> 6, lane = t & 63;
    const int m = lane & 15, q = lane >> 4;

    if (t < 128) { colsum_s[t] = 0.f; colpk_s[t] = 0u; }

    const size_t bbase = ((size_t)bb << 16);   // b * 1024 * 64 elements

    // A fragments: row = i0+32w+16rt+m, k = kb*32 + q*8 (16 B contiguous).
    bf16x8 a[2][2];
#pragma unroll
    for (int rt = 0; rt < 2; ++rt) {
        const __bf16* Ap = At + bbase + ((size_t)(i0 + 32 * w + 16 * rt + m) << 6) + q * 8;
#pragma unroll
        for (int kb = 0; kb < 2; ++kb)
            a[rt][kb] = *(const bf16x8*)(Ap + kb * 32);
    }

    f32x4 acc[2][8];
#pragma unroll
    for (int rt = 0; rt < 2; ++rt)
#pragma unroll
        for (int ct = 0; ct < 8; ++ct)
            acc[rt][ct] = (f32x4){0.f, 0.f, 0.f, 0.f};

#pragma unroll
    for (int ct = 0; ct < 8; ++ct) {
        const __bf16* Bp = Bt + bbase + ((size_t)(j0 + 16 * ct + m) << 6) + q * 8;
        bf16x8 b0 = *(const bf16x8*)(Bp);
        bf16x8 b1 = *(const bf16x8*)(Bp + 32);
        acc[0][ct] = __builtin_amdgcn_mfma_f32_16x16x32_bf16(a[0][0], b0, acc[0][ct], 0, 0, 0);
        acc[0][ct] = __builtin_amdgcn_mfma_f32_16x16x32_bf16(a[0][1], b1, acc[0][ct], 0, 0, 0);
        acc[1][ct] = __builtin_amdgcn_mfma_f32_16x16x32_bf16(a[1][0], b0, acc[1][ct], 0, 0, 0);
        acc[1][ct] = __builtin_amdgcn_mfma_f32_16x16x32_bf16(a[1][1], b1, acc[1][ct], 0, 0, 0);
    }

    // ---- epilogue: exp + row/col stats ----
    // C/D layout (verified absmax=0 in round 2): row = i0+32w+16rt+4q+r, col = j0+16ct+m.
    float    rsum[2][4]; unsigned rpk[2][4];
    float    csum[8];    unsigned cpk[8];
    unsigned iinv[2][4];
#pragma unroll
    for (int rt = 0; rt < 2; ++rt)
#pragma unroll
        for (int r = 0; r < 4; ++r) {
            rsum[rt][r] = 0.f; rpk[rt][r] = 0u;
            iinv[rt][r] = 1023u - (unsigned)(i0 + 32 * w + 16 * rt + 4 * q + r);
        }
#pragma unroll
    for (int ct = 0; ct < 8; ++ct) { csum[ct] = 0.f; cpk[ct] = 0u; }

#pragma unroll
    for (int ct = 0; ct < 8; ++ct) {
        unsigned jinv = 1023u - (unsigned)(j0 + 16 * ct + m);
#pragma unroll
        for (int rt = 0; rt < 2; ++rt)
#pragma unroll
            for (int r = 0; r < 4; ++r) {
                float e = __expf(acc[rt][ct][r] * 10.0f);
                unsigned eb = __float_as_uint(e) & 0xFFFFFC00u;
                rsum[rt][r] += e;
                unsigned prj = eb | jinv;
                if (prj > rpk[rt][r]) rpk[rt][r] = prj;
                csum[ct] += e;
                unsigned pci = eb | iinv[rt][r];
                if (pci > cpk[ct]) cpk[ct] = pci;
            }
    }

    // Row reduce across the 16 col-lanes (xor 1,2,4,8) -> global atomics.
#pragma unroll
    for (int s = 1; s < 16; s <<= 1) {
#pragma unroll
        for (int rt = 0; rt < 2; ++rt)
#pragma unroll
            for (int r = 0; r < 4; ++r) {
                rsum[rt][r] += __shfl_xor(rsum[rt][r], s, 64);
                unsigned o = (unsigned)__shfl_xor((int)rpk[rt][r], s, 64);
                if (o > rpk[rt][r]) rpk[rt][r] = o;
            }
    }
    if (m == 0) {
#pragma unroll
        for (int rt = 0; rt < 2; ++rt)
#pragma unroll
            for (int r = 0; r < 4; ++r) {
                int idx = (bb << 10) + i0 + 32 * w + 16 * rt + 4 * q + r;
                atomicAdd(&row_sum[idx], rsum[rt][r]);
                atomicMax(&row_pk[idx],  rpk[rt][r]);
            }
    }

    // Col reduce across quads (xor 16,32) -> LDS combine -> global atomics.
#pragma unroll
    for (int s = 16; s < 64; s <<= 1) {
#pragma unroll
        for (int ct = 0; ct < 8; ++ct) {
            csum[ct] += __shfl_xor(csum[ct], s, 64);
            unsigned o = (unsigned)__shfl_xor((int)cpk[ct], s, 64);
            if (o > cpk[ct]) cpk[ct] = o;
        }
    }
    __syncthreads();    // colsum_s/colpk_s init visible
    if (q == 0) {
#pragma unroll
        for (int ct = 0; ct < 8; ++ct) {
            atomicAdd(&colsum_s[16 * ct + m], csum[ct]);
            atomicMax(&colpk_s[16 * ct + m], cpk[ct]);
        }
    }
    __syncthreads();
    if (t < 128) {
        int idx = (bb << 10) + j0 + t;
        atomicAdd(&col_sum[idx], colsum_s[t]);
        atomicMax(&col_pk[idx],  colpk_s[t]);
    }
}

// Reference broadcasting: the trailing /(sum1+EPS), /(sum2+EPS) are indexed
// by ELEMENT position, not by argmax.
__global__ __launch_bounds__(256) void loss_kernel2(
        const float* __restrict__ row_sum, const unsigned* __restrict__ row_pk,
        const float* __restrict__ col_sum, const unsigned* __restrict__ col_pk,
        float* __restrict__ loss_acc) {
    int t = blockIdx.x * 256 + threadIdx.x;
    float acc = 0.f;
#pragma unroll
    for (int it = 0; it < 4; ++it) {
        int p = t + it * 16384;
        if (p < NB * LL) {
            unsigned pk2 = row_pk[p];
            float m2 = __uint_as_float(pk2 & 0xFFFFFC00u);
            int j = 1023 - (int)(pk2 & 1023u);
            float s2 = row_sum[p];
            float s1 = col_sum[p];                       // position-indexed
            unsigned pk1 = col_pk[(p & ~1023) + j];
            float m1 = __uint_as_float(pk1 & 0xFFFFFC00u);
            acc += logf((m2 / (s2 + EPS)) * (m1 / (s1 + EPS)));
        } else {
            int p2 = p - NB * LL;
            unsigned pk1 = col_pk[p2];
            float m1 = __uint_as_float(pk1 & 0xFFFFFC00u);
            int i = 1023 - (int)(pk1 & 1023u);
            float s1 = col_sum[p2];
            float s2 = row_sum[p2];                      // position-indexed
            unsigned pk2 = row_pk[(p2 & ~1023) + i];
            float m2 = __uint_as_float(pk2 & 0xFFFFFC00u);
            acc += logf((m1 / (s1 + EPS)) * (m2 / (s2 + EPS)));
        }
    }
#pragma unroll
    for (int off = 32; off > 0; off >>= 1) acc += __shfl_down(acc, off, 64);
    __shared__ float wsum[4];
    int lane = threadIdx.x & 63, w = threadIdx.x >> 6;
    if (lane == 0) wsum[w] = acc;
    __syncthreads();
    if (threadIdx.x == 0)
        atomicAdd(loss_acc, wsum[0] + wsum[1] + wsum[2] + wsum[3]);
}

__global__ void finalize_kernel(const float* __restrict__ loss_acc,
                                float* __restrict__ out) {
    out[0] = -loss_acc[0] / (float)(2 * NB * LL);
}

extern "C" void kernel_launch(void* const* d_in, const int* in_sizes, int n_in,
                              void* d_out, int out_size, void* d_ws, size_t ws_size,
                              hipStream_t stream) {
    const float* rgb = (const float*)d_in[0];
    const float* ir  = (const float*)d_in[1];
    char* wsb = (char*)d_ws;

    __bf16*   At      = (__bf16*)(wsb);
    __bf16*   Bt      = (__bf16*)(wsb + 4194304);
    float*    row_sum = (float*)(wsb + 8388608);
    float*    col_sum = (float*)(wsb + 8519680);
    unsigned* row_pk  = (unsigned*)(wsb + 8650752);
    unsigned* col_pk  = (unsigned*)(wsb + 8781824);
    float*    loss    = (float*)(wsb + 8912896);

    transpose_norm_kernel<<<1024, 256, 0, stream>>>(rgb, ir, At, Bt, row_sum);
    gemm_stats_kernel<<<2048, 256, 0, stream>>>(At, Bt, row_sum, row_pk,
                                                col_sum, col_pk);
    loss_kernel2<<<64, 256, 0, stream>>>(row_sum, row_pk, col_sum, col_pk, loss);
    finalize_kernel<<<1, 1, 0, stream>>>(loss, (float*)d_out);
}

// Round 4
// 103.390 us; speedup vs baseline: 1.0301x; 1.0301x over previous
//
#include <hip/hip_runtime.h>
#include <math.h>

#define NB 32
#define CC 64
#define LL 1024
#define EPS 1e-6f
#define SCALE 14.42695040888963f   // 10*log2(e): exp(10*s) == exp2(SCALE*s)

typedef __attribute__((ext_vector_type(8))) __bf16 bf16x8;
typedef __attribute__((ext_vector_type(4))) float f32x4;

// ws byte layout:
//   At      @ 0         (4 MB)   bf16 [32][1024][64]  rgb, normalized*SCALE, [l][c]
//   Bt      @ 4194304   (4 MB)   bf16 [32][1024][64]  ir, normalized, [l][c]
//   row_sum @ 8388608   (128 KB) f32[32768]
//   col_sum @ 8519680   (128 KB) f32[32768]
//   row_pk  @ 8650752   (128 KB) u32[32768]  (expbits&~1023)|(1023-j)
//   col_pk  @ 8781824   (128 KB) u32[32768]  (expbits&~1023)|(1023-i)
//   loss    @ 8912896   (4 B)
// Stats region zeroed inside transpose_norm (runs first; ws is 0xAA-poisoned).

__global__ __launch_bounds__(256) void transpose_norm_kernel(
        const float* __restrict__ rgb, const float* __restrict__ ir,
        __bf16* __restrict__ At, __bf16* __restrict__ Bt,
        float* __restrict__ stats_base) {
    __shared__ float tile[64][65];
    __shared__ float red[4][64];
    __shared__ float rn[64];

    const int t   = threadIdx.x;
    const int blk = blockIdx.x;

    int zid = blk * 256 + t;
    if (zid <= 131072) stats_base[zid] = 0.f;

    const int in  = blk >> 9;
    const int b   = (blk >> 4) & 31;
    const int l0  = (blk & 15) << 6;
    const float* src = in ? ir : rgb;
    __bf16*      dst = in ? Bt : At;
    const float  sc  = in ? 1.0f : SCALE;   // fold exp2 prescale into rgb side

    const int ll = t & 63, cg = t >> 6;
    const float* sp = src + ((size_t)b << 16) + l0 + ll;
#pragma unroll
    for (int u = 0; u < 16; ++u) {
        int c = cg * 16 + u;
        tile[c][ll] = sp[(size_t)c << 10];
    }
    __syncthreads();

    float ssq = 0.f;
#pragma unroll
    for (int u = 0; u < 16; ++u) {
        float v = tile[cg * 16 + u][ll];
        ssq = fmaf(v, v, ssq);
    }
    red[cg][ll] = ssq;
    __syncthreads();
    if (t < 64) {
        float s = red[0][t] + red[1][t] + red[2][t] + red[3][t];
        rn[t] = sc / fmaxf(sqrtf(s), 1e-12f);
    }
    __syncthreads();

    const int lw  = t >> 2;
    const int cg2 = t & 3;
    const float r = rn[lw];
    bf16x8 v0, v1;
#pragma unroll
    for (int u = 0; u < 8; ++u)
        v0[u] = (__bf16)(tile[cg2 * 16 + u][lw] * r);
#pragma unroll
    for (int u = 0; u < 8; ++u)
        v1[u] = (__bf16)(tile[cg2 * 16 + 8 + u][lw] * r);
    size_t base = ((((size_t)b << 10) + l0 + lw) << 6) + cg2 * 16;
    *(bf16x8*)(dst + base)     = v0;
    *(bf16x8*)(dst + base + 8) = v1;
}

// Grid 4096 = batch(32) x itile(16 of 64 rows) x jtile(8 of 128 cols).
// Register-lean: wave w owns rows [i0+16w, i0+16w+16) -> acc = 8 x f32x4 = 32
// VGPRs. __launch_bounds__(256,4) caps at 128 VGPRs -> 4 waves/SIMD (round-3
// lesson: unconstrained allocator likely killed occupancy; latency exposure,
// not staging, explains the 4-5x gap over the VALU floor).
// B staged in LDS stride-72 (2-way b128 aliasing = free); A-frags direct
// global (At rows are exact MFMA fragment order).
__global__ __launch_bounds__(256, 4) void gemm_stats_kernel(
        const __bf16* __restrict__ At, const __bf16* __restrict__ Bt,
        float* __restrict__ row_sum, unsigned* __restrict__ row_pk,
        float* __restrict__ col_sum, unsigned* __restrict__ col_pk) {
    __shared__ __bf16 Bs[128 * 72];       // 18 KB
    __shared__ float    colsum_s[128];
    __shared__ unsigned colpk_s[128];

    const int t   = threadIdx.x;
    const int blk = blockIdx.x;
    const int bb  = blk >> 7;
    const int i0  = ((blk >> 3) & 15) << 6;
    const int j0  = (blk & 7) << 7;
    const int w = t >> 6, lane = t & 63;
    const int m = lane & 15, q = lane >> 4;

    // Stage B tile (16 KB contiguous) -> padded LDS.
    {
        const __bf16* Bg = Bt + ((size_t)bb << 16) + ((size_t)j0 << 6);
#pragma unroll
        for (int it = 0; it < 4; ++it) {
            int u = t + it * 256;
            int row = u >> 3, seg = u & 7;
            *(bf16x8*)&Bs[row * 72 + seg * 8] = *(const bf16x8*)(Bg + u * 8);
        }
    }
    if (t < 128) { colsum_s[t] = 0.f; colpk_s[t] = 0u; }

    // A fragments: row = i0+16w+m, k = kb*32 + q*8.
    const __bf16* Ap = At + ((size_t)bb << 16) + ((size_t)(i0 + 16 * w + m) << 6) + q * 8;
    bf16x8 a0 = *(const bf16x8*)(Ap);
    bf16x8 a1 = *(const bf16x8*)(Ap + 32);

    __syncthreads();

    f32x4 acc[8];
#pragma unroll
    for (int ct = 0; ct < 8; ++ct) acc[ct] = (f32x4){0.f, 0.f, 0.f, 0.f};

#pragma unroll
    for (int ct = 0; ct < 8; ++ct) {
        bf16x8 b0 = *(bf16x8*)&Bs[(16 * ct + m) * 72 + q * 8];
        bf16x8 b1 = *(bf16x8*)&Bs[(16 * ct + m) * 72 + 32 + q * 8];
        acc[ct] = __builtin_amdgcn_mfma_f32_16x16x32_bf16(a0, b0, acc[ct], 0, 0, 0);
        acc[ct] = __builtin_amdgcn_mfma_f32_16x16x32_bf16(a1, b1, acc[ct], 0, 0, 0);
    }

    // ---- epilogue ----
    // C/D layout (verified rounds 2-3): row = i0+16w+4q+r, col = j0+16ct+m.
    float    rsum[4]; unsigned rpk[4]; unsigned iinv[4];
    float    csum[8]; unsigned cpk[8];
#pragma unroll
    for (int r = 0; r < 4; ++r) {
        rsum[r] = 0.f; rpk[r] = 0u;
        iinv[r] = 1023u - (unsigned)(i0 + 16 * w + 4 * q + r);
    }
#pragma unroll
    for (int ct = 0; ct < 8; ++ct) { csum[ct] = 0.f; cpk[ct] = 0u; }

#pragma unroll
    for (int ct = 0; ct < 8; ++ct) {
        unsigned jinv = 1023u - (unsigned)(j0 + 16 * ct + m);
#pragma unroll
        for (int r = 0; r < 4; ++r) {
            float e = __builtin_amdgcn_exp2f(acc[ct][r]);   // A pre-scaled by 10*log2e
            unsigned eb = __float_as_uint(e) & 0xFFFFFC00u;
            rsum[r] += e;
            csum[ct] += e;
            unsigned prj = eb | jinv;
            if (prj > rpk[r]) rpk[r] = prj;
            unsigned pci = eb | iinv[r];
            if (pci > cpk[ct]) cpk[ct] = pci;
        }
    }

    // Row reduce over 16 col-lanes (xor 1,2,4,8) -> global atomics (m==0).
#pragma unroll
    for (int s = 1; s < 16; s <<= 1) {
#pragma unroll
        for (int r = 0; r < 4; ++r) {
            rsum[r] += __shfl_xor(rsum[r], s, 64);
            unsigned o = (unsigned)__shfl_xor((int)rpk[r], s, 64);
            if (o > rpk[r]) rpk[r] = o;
        }
    }
    if (m == 0) {
#pragma unroll
        for (int r = 0; r < 4; ++r) {
            int idx = (bb << 10) + i0 + 16 * w + 4 * q + r;
            atomicAdd(&row_sum[idx], rsum[r]);
            atomicMax(&row_pk[idx],  rpk[r]);
        }
    }

    // Col reduce over quads (xor 16,32) -> LDS combine across waves -> global.
#pragma unroll
    for (int s = 16; s < 64; s <<= 1) {
#pragma unroll
        for (int ct = 0; ct < 8; ++ct) {
            csum[ct] += __shfl_xor(csum[ct], s, 64);
            unsigned o = (unsigned)__shfl_xor((int)cpk[ct], s, 64);
            if (o > cpk[ct]) cpk[ct] = o;
        }
    }
    __syncthreads();
    if (q == 0) {
#pragma unroll
        for (int ct = 0; ct < 8; ++ct) {
            atomicAdd(&colsum_s[16 * ct + m], csum[ct]);
            atomicMax(&colpk_s[16 * ct + m], cpk[ct]);
        }
    }
    __syncthreads();
    if (t < 128) {
        int idx = (bb << 10) + j0 + t;
        atomicAdd(&col_sum[idx], colsum_s[t]);
        atomicMax(&col_pk[idx],  colpk_s[t]);
    }
}

// Reference broadcasting: trailing /(sum+EPS) factors are indexed by ELEMENT
// position, not by argmax.
__global__ __launch_bounds__(256) void loss_kernel2(
        const float* __restrict__ row_sum, const unsigned* __restrict__ row_pk,
        const float* __restrict__ col_sum, const unsigned* __restrict__ col_pk,
        float* __restrict__ loss_acc) {
    int t = blockIdx.x * 256 + threadIdx.x;
    float acc = 0.f;
#pragma unroll
    for (int it = 0; it < 4; ++it) {
        int p = t + it * 16384;
        if (p < NB * LL) {
            unsigned pk2 = row_pk[p];
            float m2 = __uint_as_float(pk2 & 0xFFFFFC00u);
            int j = 1023 - (int)(pk2 & 1023u);
            float s2 = row_sum[p];
            float s1 = col_sum[p];
            unsigned pk1 = col_pk[(p & ~1023) + j];
            float m1 = __uint_as_float(pk1 & 0xFFFFFC00u);
            acc += logf((m2 / (s2 + EPS)) * (m1 / (s1 + EPS)));
        } else {
            int p2 = p - NB * LL;
            unsigned pk1 = col_pk[p2];
            float m1 = __uint_as_float(pk1 & 0xFFFFFC00u);
            int i = 1023 - (int)(pk1 & 1023u);
            float s1 = col_sum[p2];
            float s2 = row_sum[p2];
            unsigned pk2 = row_pk[(p2 & ~1023) + i];
            float m2 = __uint_as_float(pk2 & 0xFFFFFC00u);
            acc += logf((m1 / (s1 + EPS)) * (m2 / (s2 + EPS)));
        }
    }
#pragma unroll
    for (int off = 32; off > 0; off >>= 1) acc += __shfl_down(acc, off, 64);
    __shared__ float wsum[4];
    int lane = threadIdx.x & 63, w = threadIdx.x >> 6;
    if (lane == 0) wsum[w] = acc;
    __syncthreads();
    if (threadIdx.x == 0)
        atomicAdd(loss_acc, wsum[0] + wsum[1] + wsum[2] + wsum[3]);
}

__global__ void finalize_kernel(const float* __restrict__ loss_acc,
                                float* __restrict__ out) {
    out[0] = -loss_acc[0] / (float)(2 * NB * LL);
}

extern "C" void kernel_launch(void* const* d_in, const int* in_sizes, int n_in,
                              void* d_out, int out_size, void* d_ws, size_t ws_size,
                              hipStream_t stream) {
    const float* rgb = (const float*)d_in[0];
    const float* ir  = (const float*)d_in[1];
    char* wsb = (char*)d_ws;

    __bf16*   At      = (__bf16*)(wsb);
    __bf16*   Bt      = (__bf16*)(wsb + 4194304);
    float*    row_sum = (float*)(wsb + 8388608);
    float*    col_sum = (float*)(wsb + 8519680);
    unsigned* row_pk  = (unsigned*)(wsb + 8650752);
    unsigned* col_pk  = (unsigned*)(wsb + 8781824);
    float*    loss    = (float*)(wsb + 8912896);

    transpose_norm_kernel<<<1024, 256, 0, stream>>>(rgb, ir, At, Bt, row_sum);
    gemm_stats_kernel<<<4096, 256, 0, stream>>>(At, Bt, row_sum, row_pk,
                                                col_sum, col_pk);
    loss_kernel2<<<64, 256, 0, stream>>>(row_sum, row_pk, col_sum, col_pk, loss);
    finalize_kernel<<<1, 1, 0, stream>>>(loss, (float*)d_out);
}